// Round 9
// baseline (4426.455 us; speedup 1.0000x reference)
//
#include <hip/hip_runtime.h>
#include <hip/hip_bf16.h>

#define Bb 64
#define Tt 256
#define Ii 256
#define Hh 512
#define Cc 1000
#define SENT 0x7F80u  // bf16 +inf; |h|<1 so never produced
#define MAXF 1500     // fast-flag poll attempts before sticky fallback
#define MAXV 64       // fast payload verify attempts before sticky fallback

typedef float f4 __attribute__((ext_vector_type(4)));
typedef short s8 __attribute__((ext_vector_type(8)));
typedef unsigned long long u64;

__device__ __forceinline__ unsigned short f2bf(float f) {
  union { float f; unsigned u; } v; v.f = f;
  return (unsigned short)((v.u + 0x7FFFu + ((v.u >> 16) & 1u)) >> 16);
}
__device__ __forceinline__ float sigf(float x) {
  return __builtin_amdgcn_rcpf(1.f + __expf(-x));
}
__device__ __forceinline__ float tanhs(float x) {
  float ax = fabsf(x);
  float e = __expf(-2.f * ax);
  float r = (1.f - e) * __builtin_amdgcn_rcpf(1.f + e);
  return copysignf(r, x);
}

// L1-bypass (local-L2) accesses
__device__ __forceinline__ unsigned ld_sc0_u32(const unsigned* p) {
  unsigned v;
  asm volatile("global_load_dword %0, %1, off sc0\n\ts_waitcnt vmcnt(0)"
               : "=&v"(v) : "v"(p) : "memory");
  return v;
}
__device__ __forceinline__ s8 ld128_sc0(const unsigned short* p) {
  s8 v;
  asm volatile("global_load_dwordx4 %0, %1, off sc0" : "=&v"(v) : "v"(p) : "memory");
  return v;
}

struct P9 {
  const float* x;
  const float* Whh[3]; const float* Wih[3];
  const float* bih[3]; const float* bhh[3];
  unsigned short* y[3];
  unsigned* fastfl;  // [(L*32+s)*4+w]*16, plain/L2 domain, hint-only
};

__global__ void zero_flags(unsigned* f) {
  for (int i = threadIdx.x; i < 6144; i += 256) f[i] = 0;
}

// pre-fill y with sentinel (agent scope -> LLC; dispatch-boundary invalidate
// guarantees no stale L2 copies at lstm start, incl. graph replays)
__global__ void fill_y(u64* p) {
  const u64 pat = 0x7F807F807F807F80ull;
  size_t g = (size_t)blockIdx.x * 256 + threadIdx.x;
#pragma unroll
  for (int i = 0; i < 16; ++i)
    __hip_atomic_store(p + g + (size_t)i * 393216, pat, __ATOMIC_RELAXED,
                       __HIP_MEMORY_SCOPE_AGENT);
}

__global__ void bias_init_kernel(const float* __restrict__ fcb, float* __restrict__ out) {
  int i = blockIdx.x * 256 + threadIdx.x;
  if (i < Bb * Cc) out[i] = fcb[i % Cc];
}

// grid 256: L=bid&7 (<3 active -> under round-robin each layer owns one XCD, a
// HINT only), s=bid>>3 (32 slices x 16 dims). Per-wave chains (wave w: batches
// 16w..16w+15). Sync: sentinel = truth; fast flags = hint; sticky LLC fallback.
__launch_bounds__(256, 1)
__global__ void lstm_kernel(P9 p) {
  const int bid = blockIdx.x;
  const int L = bid & 7;
  if (L >= 3) return;
  const int s = bid >> 3;
  const int n0 = s * 16;
  const int tid = threadIdx.x;
  const int lane = tid & 63;
  const int w = tid >> 6;
  const int q = lane >> 4;
  const int c = lane & 15;
  const int b = 16 * w + c;

  __shared__ unsigned short Whl[64 * 512];  // 64 KB swizzled (recurrent)
  __shared__ unsigned short Wil[64 * 512];  // 64 KB (input; L0 uses 64x256)

  const int Kin = (L == 0) ? Ii : Hh;
  {  // stage: LDS row r=tt*16+rho <- gate-row (rho&3)*H + n0 + 4*(rho>>2) + tt
    const float* src = p.Whh[L];
    for (int idx = tid; idx < 64 * 64; idx += 256) {
      int r = idx >> 6, kk = (idx & 63) << 3;
      int rho = r & 15, tt = r >> 4;
      int j = (rho & 3) * Hh + n0 + 4 * (rho >> 2) + tt;
      const float* sr = src + (size_t)j * Hh + kk;
      s8 tv;
#pragma unroll
      for (int e = 0; e < 8; ++e) tv[e] = (short)f2bf(sr[e]);
      int byt = ((r * 512 + kk) * 2) ^ ((r & 7) << 4);
      *(s8*)((char*)Whl + byt) = tv;
    }
    const float* si = p.Wih[L];
    const int kd8 = Kin >> 3;
    for (int idx = tid; idx < 64 * kd8; idx += 256) {
      int r = idx / kd8, kk = (idx - r * kd8) << 3;
      int rho = r & 15, tt = r >> 4;
      int j = (rho & 3) * Hh + n0 + 4 * (rho >> 2) + tt;
      const float* sr = si + (size_t)j * Kin + kk;
      s8 tv;
#pragma unroll
      for (int e = 0; e < 8; ++e) tv[e] = (short)f2bf(sr[e]);
      int byt = ((r * Kin + kk) * 2) ^ ((r & 7) << 4);
      *(s8*)((char*)Wil + byt) = tv;
    }
  }

  f4 bias[4];
#pragma unroll
  for (int tt = 0; tt < 4; ++tt)
#pragma unroll
    for (int g = 0; g < 4; ++g) {
      int bi = g * Hh + n0 + 4 * q + tt;  // lane (q,c) tile tt -> dim n0+4q+tt
      bias[tt][g] = p.bih[L][bi] + p.bhh[L][bi];
    }
  float cst[4] = {0.f, 0.f, 0.f, 0.f};
  __syncthreads();

  const int aswz = (c & 7) << 4;
  unsigned short* yl = p.y[L];
  const unsigned short* ylow = (L > 0) ? p.y[L - 1] : (const unsigned short*)0;
  unsigned* myfl = p.fastfl + ((L * 32 + s) * 4 + w) * 16;
  bool hfast = true;  // sticky, wave-uniform (all transitions via __all)

  for (int t = 0; t < Tt; ++t) {
    f4 acc[4];
#pragma unroll
    for (int tt = 0; tt < 4; ++tt) acc[tt] = bias[tt];

    // ---- input acquisition + GEMM ----
    if (L == 0) {
      const float* xr = p.x + ((size_t)b * Tt + t) * Ii + 8 * q;
#pragma unroll
      for (int kc = 0; kc < 8; ++kc) {
        f4 xa = *(const f4*)(xr + kc * 32);
        f4 xc = *(const f4*)(xr + kc * 32 + 4);
        s8 xb;
#pragma unroll
        for (int e = 0; e < 4; ++e) { xb[e] = (short)f2bf(xa[e]); xb[e + 4] = (short)f2bf(xc[e]); }
#pragma unroll
        for (int tt = 0; tt < 4; ++tt) {
          int byt = (((tt * 16 + c) * 256 + kc * 32 + 8 * q) * 2) ^ aswz;
          s8 wa = *(const s8*)((const char*)Wil + byt);
          acc[tt] = __builtin_amdgcn_mfma_f32_16x16x32_bf16(wa, xb, acc[tt], 0, 0, 0);
        }
      }
    } else {
      // agent sentinel-poll y[L-1] row (b,t): poll IS the load (R5-proven)
      const u64* ip = (const u64*)(ylow + ((size_t)b * Tt + t) * Hh + 8 * q);
      u64 v[32];
      bool ok;
      do {
        ok = true;
#pragma unroll
        for (int kc = 0; kc < 16; ++kc) {
          v[2 * kc] = __hip_atomic_load(ip + 8 * kc, __ATOMIC_RELAXED, __HIP_MEMORY_SCOPE_AGENT);
          v[2 * kc + 1] =
              __hip_atomic_load(ip + 8 * kc + 1, __ATOMIC_RELAXED, __HIP_MEMORY_SCOPE_AGENT);
        }
#pragma unroll
        for (int e = 0; e < 32; ++e) ok &= ((((unsigned)v[e]) & 0xFFFFu) != SENT);
        ok = __all(ok);
        if (!ok) __builtin_amdgcn_s_sleep(1);
      } while (!ok);
#pragma unroll
      for (int kc = 0; kc < 16; ++kc) {
        union { u64 u[2]; s8 v8; } cv;
        cv.u[0] = v[2 * kc]; cv.u[1] = v[2 * kc + 1];
#pragma unroll
        for (int tt = 0; tt < 4; ++tt) {
          int byt = (((tt * 16 + c) * 512 + kc * 32 + 8 * q) * 2) ^ aswz;
          s8 wa = *(const s8*)((const char*)Wil + byt);
          acc[tt] = __builtin_amdgcn_mfma_f32_16x16x32_bf16(wa, cv.v8, acc[tt], 0, 0, 0);
        }
      }
    }

    // ---- h[t-1] acquisition (fast: flag-hint + sc0 + sentinel verify) ----
    if (t > 0) {
      const unsigned short* hr = yl + ((size_t)b * Tt + (t - 1)) * Hh + 8 * q;
      s8 hb[16];
      bool got = false;
      if (hfast) {
        int a = 0;
        bool fok;
        do {  // cheap 4B flag poll (lane l watches producer block l, this wave)
          unsigned v = 0xFFFFFFFFu;
          if (lane < 32) v = ld_sc0_u32(p.fastfl + ((L * 32 + lane) * 4 + w) * 16);
          fok = __all(v >= (unsigned)t);
          if (!fok) {
            if (++a > MAXF) break;
            __builtin_amdgcn_s_sleep(1);
          }
        } while (!fok);
        if (fok) {
          int va = 0;
          while (1) {  // one payload read + sentinel verify (truth)
#pragma unroll
            for (int kc = 0; kc < 16; ++kc) hb[kc] = ld128_sc0(hr + kc * 32);
            asm volatile("s_waitcnt vmcnt(0)" ::: "memory");
            __builtin_amdgcn_sched_barrier(0);
            bool ok = true;
#pragma unroll
            for (int kc = 0; kc < 16; ++kc) {
              union { s8 v8; unsigned u[4]; } cv; cv.v8 = hb[kc];
              ok &= ((cv.u[0] & 0xFFFFu) != SENT) & ((cv.u[2] & 0xFFFFu) != SENT);
            }
            if (__all(ok)) { got = true; break; }
            if (++va > MAXV) break;
            __builtin_amdgcn_s_sleep(1);
          }
        }
        if (!got) hfast = false;  // sticky: placement hint wrong for this wave
      }
      if (!got) {  // agent sentinel poll (self-validating, R5-proven)
        const u64* rp = (const u64*)hr;
        u64 v[32];
        bool ok;
        do {
          ok = true;
#pragma unroll
          for (int kc = 0; kc < 16; ++kc) {
            v[2 * kc] = __hip_atomic_load(rp + 8 * kc, __ATOMIC_RELAXED, __HIP_MEMORY_SCOPE_AGENT);
            v[2 * kc + 1] =
                __hip_atomic_load(rp + 8 * kc + 1, __ATOMIC_RELAXED, __HIP_MEMORY_SCOPE_AGENT);
          }
#pragma unroll
          for (int e = 0; e < 32; ++e) ok &= ((((unsigned)v[e]) & 0xFFFFu) != SENT);
          ok = __all(ok);
          if (!ok) __builtin_amdgcn_s_sleep(1);
        } while (!ok);
#pragma unroll
        for (int kc = 0; kc < 16; ++kc) {
          union { u64 u[2]; s8 v8; } cv;
          cv.u[0] = v[2 * kc]; cv.u[1] = v[2 * kc + 1];
          hb[kc] = cv.v8;
        }
      }
      __builtin_amdgcn_sched_barrier(0);
#pragma unroll
      for (int tt = 0; tt < 4; ++tt)
#pragma unroll
        for (int kc = 0; kc < 16; ++kc) {
          int byt = (((tt * 16 + c) * 512 + kc * 32 + 8 * q) * 2) ^ aswz;
          s8 wa = *(const s8*)((const char*)Whl + byt);
          acc[tt] = __builtin_amdgcn_mfma_f32_16x16x32_bf16(wa, hb[kc], acc[tt], 0, 0, 0);
        }
    }

    // ---- pointwise: lane (q,c) dims n0+4q+tt, gates {i,f,g,o}=acc[tt][0..3] ----
    unsigned short hu[4];
#pragma unroll
    for (int tt = 0; tt < 4; ++tt) {
      float ii = sigf(acc[tt][0]), ff = sigf(acc[tt][1]);
      float gg = tanhs(acc[tt][2]), oo = sigf(acc[tt][3]);
      cst[tt] = ff * cst[tt] + ii * gg;
      hu[tt] = f2bf(oo * tanhs(cst[tt]));
    }
    u64 hv = (u64)hu[0] | ((u64)hu[1] << 16) | ((u64)hu[2] << 32) | ((u64)hu[3] << 48);
    u64* dst = (u64*)(yl + ((size_t)b * Tt + t) * Hh + n0 + 4 * q);
    // local-L2 store -> L2 ack -> fast flag (plain) -> LLC re-store (no wait;
    // drained by next step's poll waitcnts at the latest)
    __hip_atomic_store(dst, hv, __ATOMIC_RELAXED, __HIP_MEMORY_SCOPE_WORKGROUP);
    asm volatile("s_waitcnt vmcnt(0)" ::: "memory");
    if (lane == 0)
      __hip_atomic_store(myfl, (unsigned)(t + 1), __ATOMIC_RELAXED,
                         __HIP_MEMORY_SCOPE_WORKGROUP);
    __hip_atomic_store(dst, hv, __ATOMIC_RELAXED, __HIP_MEMORY_SCOPE_AGENT);
  }
}

// out^T-tiled FC: D[c,b] += fc_w[c,k] * y2[b,k]; 32 c-tiles x 32 k-chunks, atomic f32 adds.
__launch_bounds__(256)
__global__ void fc_kernel(const float* __restrict__ w, const unsigned short* __restrict__ y2,
                          float* __restrict__ out) {
  const int ct = blockIdx.x & 31;
  const int kch = blockIdx.x >> 5;
  const int tid = threadIdx.x, lane = tid & 63, wvv = tid >> 6;
  const int b = wvv * 16 + (lane & 15);
  const int KT = Tt * Hh;  // 131072
  const int kbase = kch * 4096 + (lane >> 4) * 8;
  const int c0 = ct * 32 + (lane & 15);
  const int c1 = c0 + 16;
  const bool v0 = (c0 < Cc), v1 = (c1 < Cc);
  const float* w0 = w + (size_t)c0 * KT;
  const float* w1 = w + (size_t)c1 * KT;
  const unsigned short* yr = y2 + (size_t)b * KT;
  f4 a0 = {0.f, 0.f, 0.f, 0.f}, a1 = {0.f, 0.f, 0.f, 0.f};
  for (int kk = 0; kk < 4096; kk += 32) {
    const int k = kbase + kk;
    s8 bf = *(const s8*)(yr + k);
    s8 wa0 = {0, 0, 0, 0, 0, 0, 0, 0}, wa1 = {0, 0, 0, 0, 0, 0, 0, 0};
    if (v0) {
#pragma unroll
      for (int qq = 0; qq < 8; ++qq) wa0[qq] = (short)f2bf(w0[k + qq]);
    }
    if (v1) {
#pragma unroll
      for (int qq = 0; qq < 8; ++qq) wa1[qq] = (short)f2bf(w1[k + qq]);
    }
    a0 = __builtin_amdgcn_mfma_f32_16x16x32_bf16(wa0, bf, a0, 0, 0, 0);
    a1 = __builtin_amdgcn_mfma_f32_16x16x32_bf16(wa1, bf, a1, 0, 0, 0);
  }
  const int rr = (lane >> 4) * 4;
#pragma unroll
  for (int qq = 0; qq < 4; ++qq) {
    int ca = ct * 32 + rr + qq;
    if (ca < Cc) atomicAdd(out + (size_t)b * Cc + ca, a0[qq]);
    int cb2 = ca + 16;
    if (cb2 < Cc) atomicAdd(out + (size_t)b * Cc + cb2, a1[qq]);
  }
}

extern "C" void kernel_launch(void* const* d_in, const int* in_sizes, int n_in,
                              void* d_out, int out_size, void* d_ws, size_t ws_size,
                              hipStream_t stream) {
  P9 p;
  p.x = (const float*)d_in[0];
  p.Wih[0] = (const float*)d_in[1];  p.Whh[0] = (const float*)d_in[2];
  p.bih[0] = (const float*)d_in[3];  p.bhh[0] = (const float*)d_in[4];
  p.Wih[1] = (const float*)d_in[5];  p.Whh[1] = (const float*)d_in[6];
  p.bih[1] = (const float*)d_in[7];  p.bhh[1] = (const float*)d_in[8];
  p.Wih[2] = (const float*)d_in[9];  p.Whh[2] = (const float*)d_in[10];
  p.bih[2] = (const float*)d_in[11]; p.bhh[2] = (const float*)d_in[12];
  const float* fcw = (const float*)d_in[13];
  const float* fcb = (const float*)d_in[14];

  char* ws = (char*)d_ws;
  p.fastfl = (unsigned*)ws;  // 24 KB spread flag lines
  const size_t ysz = (size_t)Bb * Tt * Hh;
  unsigned short* y0 = (unsigned short*)(ws + 32768);
  p.y[0] = y0;
  p.y[1] = y0 + ysz;
  p.y[2] = y0 + 2 * ysz;

  zero_flags<<<1, 256, 0, stream>>>(p.fastfl);
  fill_y<<<1536, 256, 0, stream>>>((u64*)y0);  // 3*ysz*2 B = 6291456 u64 exactly
  bias_init_kernel<<<250, 256, 0, stream>>>(fcb, (float*)d_out);
  lstm_kernel<<<256, 256, 0, stream>>>(p);
  fc_kernel<<<1024, 256, 0, stream>>>(fcw, p.y[2], (float*)d_out);
}

// Round 10
// 2286.213 us; speedup vs baseline: 1.9362x; 1.9362x over previous
//
#include <hip/hip_runtime.h>
#include <hip/hip_bf16.h>

#define Bb 64
#define Tt 256
#define Ii 256
#define Hh 512
#define Cc 1000

typedef float f4 __attribute__((ext_vector_type(4)));
typedef short s8 __attribute__((ext_vector_type(8)));
typedef unsigned long long u64;

__device__ __forceinline__ unsigned short f2bf(float f) {
  union { float f; unsigned u; } v; v.f = f;
  return (unsigned short)((v.u + 0x7FFFu + ((v.u >> 16) & 1u)) >> 16);
}
__device__ __forceinline__ float sigf(float x) {
  return __builtin_amdgcn_rcpf(1.f + __expf(-x));
}
__device__ __forceinline__ float tanhs(float x) {
  float ax = fabsf(x);
  float e = __expf(-2.f * ax);
  float r = (1.f - e) * __builtin_amdgcn_rcpf(1.f + e);
  return copysignf(r, x);
}

struct PX {
  const float* x;
  const float* Whh[3]; const float* Wih[3];
  const float* bih[3]; const float* bhh[3];
  const float* fcw;
  float* outbuf;
  unsigned short* y[3];
  unsigned* cnt;  // [3][4][256] step counters, one 64B line each (idx*16)
};

__global__ void zero_cnt(unsigned* f) {
  int i = blockIdx.x * 256 + threadIdx.x;
  if (i < 3 * 4 * 256 * 16) f[i] = 0;
}

__global__ void bias_init_kernel(const float* __restrict__ fcb, float* __restrict__ out) {
  int i = blockIdx.x * 256 + threadIdx.x;
  if (i < Bb * Cc) out[i] = fcb[i % Cc];
}

// grid 256, 1 block/CU. bid<96: LSTM (L=bid>>5, s=bid&31, 16 dims/slice,
// per-wave batch chains). bid>=96: FC (160 blocks grid-striding 1024 tiles,
// counter-gated so fc_w streaming hides under the recurrence).
// Sync: h stores = atomic_exchange (execute AT the LLC); one aggregated
// counter per (L,wave,t); consumers poll a single broadcast u32.
__launch_bounds__(256, 1)
__global__ void mega_kernel(PX p) {
  const int bid = blockIdx.x;
  const int tid = threadIdx.x;
  const int lane = tid & 63;
  const int w = tid >> 6;
  const int q = lane >> 4;
  const int c = lane & 15;

  __shared__ unsigned short Whl[64 * 512];  // 64 KB swizzled (recurrent)
  __shared__ unsigned short Wil[64 * 512];  // 64 KB (input; L0 uses 64x256)

  if (bid < 96) {
    const int L = bid >> 5;
    const int s = bid & 31;
    const int n0 = s * 16;
    const int b = 16 * w + c;

    const int Kin = (L == 0) ? Ii : Hh;
    {  // stage: LDS row r=tt*16+rho <- gate-row (rho&3)*H + n0 + 4*(rho>>2) + tt
      const float* src = p.Whh[L];
      for (int idx = tid; idx < 64 * 64; idx += 256) {
        int r = idx >> 6, kk = (idx & 63) << 3;
        int rho = r & 15, tt = r >> 4;
        int j = (rho & 3) * Hh + n0 + 4 * (rho >> 2) + tt;
        const float* sr = src + (size_t)j * Hh + kk;
        s8 tv;
#pragma unroll
        for (int e = 0; e < 8; ++e) tv[e] = (short)f2bf(sr[e]);
        int byt = ((r * 512 + kk) * 2) ^ ((r & 7) << 4);
        *(s8*)((char*)Whl + byt) = tv;
      }
      const float* si = p.Wih[L];
      const int kd8 = Kin >> 3;
      for (int idx = tid; idx < 64 * kd8; idx += 256) {
        int r = idx / kd8, kk = (idx - r * kd8) << 3;
        int rho = r & 15, tt = r >> 4;
        int j = (rho & 3) * Hh + n0 + 4 * (rho >> 2) + tt;
        const float* sr = si + (size_t)j * Kin + kk;
        s8 tv;
#pragma unroll
        for (int e = 0; e < 8; ++e) tv[e] = (short)f2bf(sr[e]);
        int byt = ((r * Kin + kk) * 2) ^ ((r & 7) << 4);
        *(s8*)((char*)Wil + byt) = tv;
      }
    }

    f4 bias[4];
#pragma unroll
    for (int tt = 0; tt < 4; ++tt)
#pragma unroll
      for (int g = 0; g < 4; ++g) {
        int bi = g * Hh + n0 + 4 * q + tt;  // lane (q,c) tile tt -> dim n0+4q+tt
        bias[tt][g] = p.bih[L][bi] + p.bhh[L][bi];
      }
    float cst[4] = {0.f, 0.f, 0.f, 0.f};
    __syncthreads();

    const int aswz = (c & 7) << 4;
    unsigned short* yl = p.y[L];
    const unsigned short* ylow = (L > 0) ? p.y[L - 1] : (const unsigned short*)0;
    unsigned* cin = (L > 0) ? p.cnt + ((L - 1) * 4 + w) * 256 * 16 : (unsigned*)0;
    unsigned* cown = p.cnt + (L * 4 + w) * 256 * 16;

    for (int t = 0; t < Tt; ++t) {
      f4 acc[4];
#pragma unroll
      for (int tt = 0; tt < 4; ++tt) acc[tt] = bias[tt];

      if (L == 0) {
        const float* xr = p.x + ((size_t)b * Tt + t) * Ii + 8 * q;
#pragma unroll
        for (int kc = 0; kc < 8; ++kc) {
          f4 xa = *(const f4*)(xr + kc * 32);
          f4 xc = *(const f4*)(xr + kc * 32 + 4);
          s8 xb;
#pragma unroll
          for (int e = 0; e < 4; ++e) { xb[e] = (short)f2bf(xa[e]); xb[e + 4] = (short)f2bf(xc[e]); }
#pragma unroll
          for (int tt = 0; tt < 4; ++tt) {
            int byt = (((tt * 16 + c) * 256 + kc * 32 + 8 * q) * 2) ^ aswz;
            s8 wa = *(const s8*)((const char*)Wil + byt);
            acc[tt] = __builtin_amdgcn_mfma_f32_16x16x32_bf16(wa, xb, acc[tt], 0, 0, 0);
          }
        }
      } else {
        while (__hip_atomic_load(cin + t * 16, __ATOMIC_RELAXED, __HIP_MEMORY_SCOPE_AGENT) < 32u)
          __builtin_amdgcn_s_sleep(1);
        asm volatile("" ::: "memory");
        const unsigned short* yr = ylow + ((size_t)b * Tt + t) * Hh + 8 * q;
        s8 yb[16];
#pragma unroll
        for (int kc = 0; kc < 16; ++kc) yb[kc] = *(const s8*)(yr + kc * 32);
#pragma unroll
        for (int tt = 0; tt < 4; ++tt)
#pragma unroll
          for (int kc = 0; kc < 16; ++kc) {
            int byt = (((tt * 16 + c) * 512 + kc * 32 + 8 * q) * 2) ^ aswz;
            s8 wa = *(const s8*)((const char*)Wil + byt);
            acc[tt] = __builtin_amdgcn_mfma_f32_16x16x32_bf16(wa, yb[kc], acc[tt], 0, 0, 0);
          }
      }

      if (t > 0) {
        while (__hip_atomic_load(cown + (t - 1) * 16, __ATOMIC_RELAXED,
                                 __HIP_MEMORY_SCOPE_AGENT) < 32u)
          __builtin_amdgcn_s_sleep(1);
        asm volatile("" ::: "memory");
        const unsigned short* hr = yl + ((size_t)b * Tt + (t - 1)) * Hh + 8 * q;
        s8 hb[16];
#pragma unroll
        for (int kc = 0; kc < 16; ++kc) hb[kc] = *(const s8*)(hr + kc * 32);
#pragma unroll
        for (int tt = 0; tt < 4; ++tt)
#pragma unroll
          for (int kc = 0; kc < 16; ++kc) {
            int byt = (((tt * 16 + c) * 512 + kc * 32 + 8 * q) * 2) ^ aswz;
            s8 wa = *(const s8*)((const char*)Whl + byt);
            acc[tt] = __builtin_amdgcn_mfma_f32_16x16x32_bf16(wa, hb[kc], acc[tt], 0, 0, 0);
          }
      }

      unsigned short hu[4];
#pragma unroll
      for (int tt = 0; tt < 4; ++tt) {
        float ii = sigf(acc[tt][0]), ff = sigf(acc[tt][1]);
        float gg = tanhs(acc[tt][2]), oo = sigf(acc[tt][3]);
        cst[tt] = ff * cst[tt] + ii * gg;
        hu[tt] = f2bf(oo * tanhs(cst[tt]));
      }
      u64 hv = (u64)hu[0] | ((u64)hu[1] << 16) | ((u64)hu[2] << 32) | ((u64)hu[3] << 48);
      u64* dst = (u64*)(yl + ((size_t)b * Tt + t) * Hh + n0 + 4 * q);
      (void)__hip_atomic_exchange(dst, hv, __ATOMIC_RELAXED, __HIP_MEMORY_SCOPE_AGENT);
      asm volatile("s_waitcnt vmcnt(0)" ::: "memory");
      if (lane == 0) atomicAdd(cown + t * 16, 1u);
    }
  } else {
    // FC role
    const int fcid = bid - 96;
    const int KT = Tt * Hh;
    const int b = 16 * w + c;
    const unsigned short* y2 = p.y[2];
    for (int ti = fcid; ti < 1024; ti += 160) {
      const int kch = ti >> 5, ct = ti & 31;
      const int tneed = kch * 8 + 7;
      bool ok;
      do {
        unsigned v = 32u;
        if (lane < 4)
          v = __hip_atomic_load(p.cnt + ((2 * 4 + lane) * 256 + tneed) * 16,
                                __ATOMIC_RELAXED, __HIP_MEMORY_SCOPE_AGENT);
        ok = __all(v >= 32u);
        if (!ok) __builtin_amdgcn_s_sleep(8);
      } while (!ok);
      asm volatile("" ::: "memory");

      const int kbase = kch * 4096 + q * 8;
      const int c0 = ct * 32 + c;
      const int c1 = c0 + 16;
      const bool v0 = (c0 < Cc), v1 = (c1 < Cc);
      const float* w0 = p.fcw + (size_t)c0 * KT;
      const float* w1 = p.fcw + (size_t)c1 * KT;
      const unsigned short* yr = y2 + (size_t)b * KT;
      f4 a0 = {0.f, 0.f, 0.f, 0.f}, a1 = {0.f, 0.f, 0.f, 0.f};
      for (int kk = 0; kk < 4096; kk += 32) {
        const int k = kbase + kk;
        s8 bf = *(const s8*)(yr + k);
        s8 wa0 = {0, 0, 0, 0, 0, 0, 0, 0}, wa1 = {0, 0, 0, 0, 0, 0, 0, 0};
        if (v0) {
#pragma unroll
          for (int qq = 0; qq < 8; ++qq) wa0[qq] = (short)f2bf(w0[k + qq]);
        }
        if (v1) {
#pragma unroll
          for (int qq = 0; qq < 8; ++qq) wa1[qq] = (short)f2bf(w1[k + qq]);
        }
        a0 = __builtin_amdgcn_mfma_f32_16x16x32_bf16(wa0, bf, a0, 0, 0, 0);
        a1 = __builtin_amdgcn_mfma_f32_16x16x32_bf16(wa1, bf, a1, 0, 0, 0);
      }
      const int rr = q * 4;
#pragma unroll
      for (int qq = 0; qq < 4; ++qq) {
        int ca = ct * 32 + rr + qq;
        if (ca < Cc) atomicAdd(p.outbuf + (size_t)b * Cc + ca, a0[qq]);
        int cb2 = ca + 16;
        if (cb2 < Cc) atomicAdd(p.outbuf + (size_t)b * Cc + cb2, a1[qq]);
      }
    }
  }
}

extern "C" void kernel_launch(void* const* d_in, const int* in_sizes, int n_in,
                              void* d_out, int out_size, void* d_ws, size_t ws_size,
                              hipStream_t stream) {
  PX p;
  p.x = (const float*)d_in[0];
  p.Wih[0] = (const float*)d_in[1];  p.Whh[0] = (const float*)d_in[2];
  p.bih[0] = (const float*)d_in[3];  p.bhh[0] = (const float*)d_in[4];
  p.Wih[1] = (const float*)d_in[5];  p.Whh[1] = (const float*)d_in[6];
  p.bih[1] = (const float*)d_in[7];  p.bhh[1] = (const float*)d_in[8];
  p.Wih[2] = (const float*)d_in[9];  p.Whh[2] = (const float*)d_in[10];
  p.bih[2] = (const float*)d_in[11]; p.bhh[2] = (const float*)d_in[12];
  p.fcw = (const float*)d_in[13];
  const float* fcb = (const float*)d_in[14];
  p.outbuf = (float*)d_out;

  char* ws = (char*)d_ws;
  p.cnt = (unsigned*)ws;  // 192 KB padded counters
  const size_t ysz = (size_t)Bb * Tt * Hh;
  unsigned short* y0 = (unsigned short*)(ws + 196608);
  p.y[0] = y0;
  p.y[1] = y0 + ysz;
  p.y[2] = y0 + 2 * ysz;

  zero_cnt<<<192, 256, 0, stream>>>(p.cnt);
  bias_init_kernel<<<250, 256, 0, stream>>>(fcb, (float*)d_out);
  mega_kernel<<<256, 256, 0, stream>>>(p);
}